// Round 2
// baseline (6734.014 us; speedup 1.0000x reference)
//
#include <hip/hip_runtime.h>
#include <cstdint>
#include <cstddef>

// JAX >= 0.4.30 defaults jax_threefry_partitionable=True. If Output 2
// (log_prob sum) fails while Output 1 (entropy) passes, flip this to 0.
#define JAX_PARTITIONABLE 1

#define NSTEPS 96
#define HID 1024
#define NBLK 256
#define NTHR 256

// ws layout (floats): [4][1024] h double-buffers; cnt/gen at [4096],[4097]
#define WS_BAR_OFF 4096

// ---------------- Threefry-2x32-20 (exact JAX algorithm) ----------------
__device__ __forceinline__ void tf2x32(uint32_t k0, uint32_t k1,
                                       uint32_t x0, uint32_t x1,
                                       uint32_t& o0, uint32_t& o1) {
  uint32_t ks[3] = {k0, k1, k0 ^ k1 ^ 0x1BD11BDAu};
  x0 += ks[0];
  x1 += ks[1];
  const uint32_t R[2][4] = {{13u, 15u, 26u, 6u}, {17u, 29u, 16u, 24u}};
#pragma unroll
  for (int i = 0; i < 5; ++i) {
#pragma unroll
    for (int r = 0; r < 4; ++r) {
      uint32_t rot = R[i & 1][r];
      x0 += x1;
      x1 = (x1 << rot) | (x1 >> (32u - rot));
      x1 ^= x0;
    }
    x0 += ks[(i + 1) % 3];
    x1 += ks[(i + 2) % 3] + (uint32_t)(i + 1);
  }
  o0 = x0;
  o1 = x1;
}

// JAX uniform(minval=tiny, maxval=1) from 32 random bits
__device__ __forceinline__ float jax_uniform(uint32_t bits) {
  const float TINY = 1.17549435e-38f;
  float f = __uint_as_float((bits >> 9) | 0x3f800000u) - 1.0f;
  f = f * (1.0f - TINY) + TINY;
  return fmaxf(TINY, f);
}

__device__ __forceinline__ float sigmoidf_(float x) {
  return 1.0f / (1.0f + expf(-x));
}

// Hand-rolled grid barrier: release/acquire chain at agent (device) scope.
// All 256 blocks are guaranteed resident (launch_bounds caps VGPR at 128 ->
// >=2 blocks/CU capacity on 256 CUs), so spinning cannot deadlock.
__device__ __forceinline__ void gridbar(unsigned* cnt, unsigned* gen) {
  __syncthreads();
  if (threadIdx.x == 0) {
    unsigned g = __hip_atomic_load(gen, __ATOMIC_RELAXED, __HIP_MEMORY_SCOPE_AGENT);
    unsigned old = __hip_atomic_fetch_add(cnt, 1u, __ATOMIC_ACQ_REL, __HIP_MEMORY_SCOPE_AGENT);
    if (old == NBLK - 1) {
      __hip_atomic_store(cnt, 0u, __ATOMIC_RELAXED, __HIP_MEMORY_SCOPE_AGENT);
      __hip_atomic_fetch_add(gen, 1u, __ATOMIC_ACQ_REL, __HIP_MEMORY_SCOPE_AGENT);
    } else {
      while (__hip_atomic_load(gen, __ATOMIC_ACQUIRE, __HIP_MEMORY_SCOPE_AGENT) == g) {
        __builtin_amdgcn_s_sleep(2);
      }
    }
  }
  __syncthreads();
}

// 256 blocks x 256 threads. Block b owns hidden units [b*4, b*4+4) of both
// layers: 16 gate rows (i,f,g,o quadrants x 4 units). Thread = (row_idx, sub):
// row_idx = tid>>4 in [0,16), sub = tid&15 covers k-slice [sub*64, sub*64+64).
// c-state in LDS of the owning block; h crosses blocks via ws (double-buffered
// per layer). 2 grid barriers per step; logits+sampling computed redundantly
// and bit-identically in every block.
__global__ void __launch_bounds__(NTHR, 2)
enas_controller(const float* __restrict__ g_emb,   // [1,1024]
                const float* __restrict__ w_emb,   // [8,1024]
                const float* __restrict__ w_soft,  // [2,1024]
                const float* __restrict__ w_ih,    // [2,4096,1024]
                const float* __restrict__ w_hh,    // [2,4096,1024]
                const float* __restrict__ b_ih,    // [2,4096]
                const float* __restrict__ b_hh,    // [2,4096]
                float* __restrict__ out,           // [98]
                float* __restrict__ ws) {          // >= 4098 floats, zeroed
  unsigned* cnt = (unsigned*)(ws + WS_BAR_OFF);
  unsigned* gen = cnt + 1;

  const int tid = threadIdx.x;
  const int b = blockIdx.x;
  const int row_idx = tid >> 4;
  const int sub = tid & 15;
  const int k0 = sub * 64;
  const int q = row_idx >> 2;
  const int j = row_idx & 3;
  const int row = q * HID + (b * 4 + j);  // gate row within one layer's 4096

  __shared__ float pIH[16][16];
  __shared__ float pHH[16][16];
  __shared__ float gatesS[16];
  __shared__ float cS[2][4];
  __shared__ float red0[NTHR];
  __shared__ float red1[NTHR];
  __shared__ float logitS[2];

  if (tid < 8) cS[tid >> 2][tid & 3] = 0.0f;
  __syncthreads();

  int sample = -1;  // -1 => use g_emb row 0 as step-0 input
  float accE = 0.0f, accLP = 0.0f;

  for (int s = 0; s < NSTEPS; ++s) {
    const int par = s & 1;

    for (int l = 0; l < 2; ++l) {
      // h buffer layout in ws: [(layer*2 + parity)][1024]
      const float* xsrc;
      if (l == 0)
        xsrc = (sample < 0) ? g_emb : (w_emb + (size_t)sample * HID);
      else
        xsrc = ws + (size_t)(0 * 2 + par) * HID;        // h1 (fresh this step)
      const float* hsrc = ws + (size_t)(l * 2 + (par ^ 1)) * HID;
      float* hdst = ws + (size_t)(l * 2 + par) * HID;
      const bool hzero = (s == 0);

      const float* wrow_ih = w_ih + ((size_t)l * 4096 + row) * HID + k0;
      const float* wrow_hh = w_hh + ((size_t)l * 4096 + row) * HID + k0;

      float aih = 0.0f, ahh = 0.0f;
      {
        const float4* w4 = (const float4*)wrow_ih;
        const float4* x4 = (const float4*)(xsrc + k0);
#pragma unroll
        for (int i = 0; i < 16; ++i) {
          float4 wv = w4[i], xv = x4[i];
          aih += wv.x * xv.x; aih += wv.y * xv.y;
          aih += wv.z * xv.z; aih += wv.w * xv.w;
        }
      }
      if (!hzero) {
        const float4* w4 = (const float4*)wrow_hh;
        const float4* h4 = (const float4*)(hsrc + k0);
#pragma unroll
        for (int i = 0; i < 16; ++i) {
          float4 wv = w4[i], hv = h4[i];
          ahh += wv.x * hv.x; ahh += wv.y * hv.y;
          ahh += wv.z * hv.z; ahh += wv.w * hv.w;
        }
      }
      pIH[row_idx][sub] = aih;
      pHH[row_idx][sub] = ahh;
      __syncthreads();

      if (tid < 16) {
        float sih = 0.0f, shh = 0.0f;
#pragma unroll
        for (int u = 0; u < 16; ++u) { sih += pIH[tid][u]; shh += pHH[tid][u]; }
        const int rr = (tid >> 2) * HID + (b * 4 + (tid & 3));
        const int bidx = l * 4096 + rr;
        // gates = ((W_ih@x + b_ih) + W_hh@h) + b_hh  (reference add order)
        gatesS[tid] = (sih + b_ih[bidx]) + shh + b_hh[bidx];
      }
      __syncthreads();

      if (tid < 4) {
        float gi = gatesS[tid], gf = gatesS[4 + tid];
        float gg = gatesS[8 + tid], go = gatesS[12 + tid];
        float c = cS[l][tid];
        float cn = sigmoidf_(gf) * c + sigmoidf_(gi) * tanhf(gg);
        float hn = sigmoidf_(go) * tanhf(cn);
        cS[l][tid] = cn;
        hdst[b * 4 + tid] = hn;
      }
      gridbar(cnt, gen);  // h(l) visible to all blocks
    }

    // ---- logits + sampling: redundantly, bit-identically in every block ----
    {
      const float* h2 = ws + (size_t)(1 * 2 + par) * HID;
      const int k = tid * 4;
      float p0 = 0.0f, p1 = 0.0f;
#pragma unroll
      for (int i = 0; i < 4; ++i) {
        float hv = h2[k + i];
        p0 += w_soft[k + i] * hv;
        p1 += w_soft[HID + k + i] * hv;
      }
      red0[tid] = p0;
      red1[tid] = p1;
      __syncthreads();
      for (int off = NTHR / 2; off > 0; off >>= 1) {
        if (tid < off) { red0[tid] += red0[tid + off]; red1[tid] += red1[tid + off]; }
        __syncthreads();
      }
      if (tid == 0) {
        logitS[0] = 2.5f * tanhf(red0[0] / 5.0f);
        logitS[1] = 2.5f * tanhf(red1[0] / 5.0f);
      }
      __syncthreads();
      const float l0 = logitS[0], l1 = logitS[1];

      // log_softmax (JAX formulation)
      float m = fmaxf(l0, l1);
      float s0 = l0 - m, s1 = l1 - m;
      float lse = logf(expf(s0) + expf(s1));
      float lp0 = s0 - lse, lp1 = s1 - lse;

      uint32_t sk0, sk1, bt0, bt1;
#if JAX_PARTITIONABLE
      // subkey_s = threefry((0,42), (0,s)); bits_i = w0^w1 of threefry(subkey,(0,i))
      tf2x32(0u, 42u, 0u, (uint32_t)s, sk0, sk1);
      { uint32_t a, c; tf2x32(sk0, sk1, 0u, 0u, a, c); bt0 = a ^ c; }
      { uint32_t a, c; tf2x32(sk0, sk1, 0u, 1u, a, c); bt1 = a ^ c; }
#else
      // legacy split: flat = concat(w0s, w1s) of threefry((0,42), ([0..95],[96..191]))
      {
        uint32_t a0, a1, c0, c1;
        if (s < 48) {
          tf2x32(0u, 42u, (uint32_t)(2 * s),     (uint32_t)(96 + 2 * s), a0, c0);
          tf2x32(0u, 42u, (uint32_t)(2 * s + 1), (uint32_t)(97 + 2 * s), a1, c1);
          sk0 = a0; sk1 = a1;
        } else {
          tf2x32(0u, 42u, (uint32_t)(2 * s - 96), (uint32_t)(2 * s),     a0, c0);
          tf2x32(0u, 42u, (uint32_t)(2 * s - 95), (uint32_t)(2 * s + 1), a1, c1);
          sk0 = c0; sk1 = c1;
        }
        uint32_t a, c;
        tf2x32(sk0, sk1, 0u, 1u, a, c);  // counts [0,1] in one call
        bt0 = a; bt1 = c;
      }
#endif
      float gum0 = -logf(-logf(jax_uniform(bt0)));
      float gum1 = -logf(-logf(jax_uniform(bt1)));
      sample = (gum1 + l1 > gum0 + l0) ? 1 : 0;  // argmax, ties -> index 0

      accE += -(expf(lp0) * lp0 + expf(lp1) * lp1);
      accLP += sample ? lp1 : lp0;
      if (b == 0 && tid == 0) out[s] = (float)sample;
    }
    // next step's layer-0 only needs local 'sample' + synced h buffers
  }

  if (b == 0 && tid == 0) {
    out[96] = accE;
    out[97] = accLP;
  }
}

extern "C" void kernel_launch(void* const* d_in, const int* in_sizes, int n_in,
                              void* d_out, int out_size, void* d_ws, size_t ws_size,
                              hipStream_t stream) {
  const float* g_emb = (const float*)d_in[0];
  const float* w_emb = (const float*)d_in[1];
  const float* w_soft = (const float*)d_in[2];
  const float* w_ih = (const float*)d_in[3];
  const float* w_hh = (const float*)d_in[4];
  const float* b_ih = (const float*)d_in[5];
  const float* b_hh = (const float*)d_in[6];
  float* out = (float*)d_out;
  float* ws = (float*)d_ws;

  // h buffers + barrier words must start zeroed (harness poisons ws with 0xAA)
  hipMemsetAsync(ws, 0, (WS_BAR_OFF + 8) * sizeof(float), stream);

  enas_controller<<<dim3(NBLK), dim3(NTHR), 0, stream>>>(
      g_emb, w_emb, w_soft, w_ih, w_hh, b_ih, b_hh, out, ws);
}

// Round 3
// 4519.690 us; speedup vs baseline: 1.4899x; 1.4899x over previous
//
#include <hip/hip_runtime.h>
#include <cstdint>
#include <cstddef>

#define NSTEPS 96
#define HID 1024
#define NBLK 256
#define NTHR 512

// ws layout (float offsets)
#define WS_H0    0          // [2][1024] layer-0 h double buffer
#define WS_H1    2048       // [2][1024] layer-1 h double buffer
#define WS_P0    4096       // [256] partial logit 0 per block
#define WS_P1    4352       // [256] partial logit 1 per block
#define WS_FLAGS 4608       // 256 flags, one per 32-float (128B) line
#define WS_GENA  12800      // phase-A generation word (own line)
#define WS_GENB  12832      // phase-B generation word: (epoch<<1)|sample
#define WS_TOTAL 12864

// ---------------- Threefry-2x32-20 (exact JAX algorithm) ----------------
__device__ __forceinline__ void tf2x32(uint32_t k0, uint32_t k1,
                                       uint32_t x0, uint32_t x1,
                                       uint32_t& o0, uint32_t& o1) {
  uint32_t ks[3] = {k0, k1, k0 ^ k1 ^ 0x1BD11BDAu};
  x0 += ks[0];
  x1 += ks[1];
  const uint32_t R[2][4] = {{13u, 15u, 26u, 6u}, {17u, 29u, 16u, 24u}};
#pragma unroll
  for (int i = 0; i < 5; ++i) {
#pragma unroll
    for (int r = 0; r < 4; ++r) {
      uint32_t rot = R[i & 1][r];
      x0 += x1;
      x1 = (x1 << rot) | (x1 >> (32u - rot));
      x1 ^= x0;
    }
    x0 += ks[(i + 1) % 3];
    x1 += ks[(i + 2) % 3] + (uint32_t)(i + 1);
  }
  o0 = x0;
  o1 = x1;
}

__device__ __forceinline__ float jax_uniform(uint32_t bits) {
  const float TINY = 1.17549435e-38f;
  float f = __uint_as_float((bits >> 9) | 0x3f800000u) - 1.0f;
  f = f * (1.0f - TINY) + TINY;
  return fmaxf(TINY, f);
}

__device__ __forceinline__ float sigmoidf_(float x) {
  return 1.0f / (1.0f + expf(-x));
}

// 256 blocks x 512 threads. Block b owns hidden units [4b,4b+4) of both
// layers. Thread = (row_idx = tid>>5 in [0,16), sub = tid&31). Each thread
// holds its k-slice of 4 weight rows IN REGISTERS (32 float4 = 128 VGPRs),
// columns interleaved: col = sub*4 + i*128 (coalesced global, conflict-free
// LDS). Weights are loaded once; the 96-step loop touches only h vectors.
// Grid sync: per-block flag lines + block-0 central gather + one gen word.
__global__ void __launch_bounds__(NTHR, 1)
enas_controller(const float* __restrict__ g_emb,   // [1,1024]
                const float* __restrict__ w_emb,   // [8,1024]
                const float* __restrict__ w_soft,  // [2,1024]
                const float* __restrict__ w_ih,    // [2,4096,1024]
                const float* __restrict__ w_hh,    // [2,4096,1024]
                const float* __restrict__ b_ih,    // [2,4096]
                const float* __restrict__ b_hh,    // [2,4096]
                float* __restrict__ out,           // [98]
                float* __restrict__ ws) {          // >= WS_TOTAL floats, zeroed
  const int tid = threadIdx.x;
  const int b = blockIdx.x;
  const int row_idx = tid >> 5;
  const int sub = tid & 31;
  const int q = row_idx >> 2;
  const int j = row_idx & 3;
  const int row = q * HID + (b * 4 + j);  // gate row within one layer's 4096
  const int col0 = sub * 4;               // + i*128 interleave

  unsigned* flags = (unsigned*)(ws + WS_FLAGS);
  unsigned* genA = (unsigned*)(ws + WS_GENA);
  unsigned* genB = (unsigned*)(ws + WS_GENB);
  float* h0buf = ws + WS_H0;
  float* h1buf = ws + WS_H1;
  float* part0 = ws + WS_P0;
  float* part1 = ws + WS_P1;

  __shared__ __align__(16) float embS[9 * HID];  // rows 0-7 w_emb, row 8 g_emb
  __shared__ float bsumS[2][16];
  __shared__ float wsoftS[2][4];
  __shared__ float gatesS[16];
  __shared__ float cS[2][4];
  __shared__ __align__(16) float hS[4];
  __shared__ float wredS[2][8];
  __shared__ int sampS;

  // ---- one-time: weights into VGPRs ----
  float4 Wih0[8], Whh0[8], Wih1[8], Whh1[8];
  {
    const float* p_ih0 = w_ih + (size_t)row * HID;
    const float* p_ih1 = w_ih + (size_t)(4096 + row) * HID;
    const float* p_hh0 = w_hh + (size_t)row * HID;
    const float* p_hh1 = w_hh + (size_t)(4096 + row) * HID;
#pragma unroll
    for (int i = 0; i < 8; ++i) {
      Wih0[i] = *(const float4*)(p_ih0 + col0 + i * 128);
      Whh0[i] = *(const float4*)(p_hh0 + col0 + i * 128);
      Wih1[i] = *(const float4*)(p_ih1 + col0 + i * 128);
      Whh1[i] = *(const float4*)(p_hh1 + col0 + i * 128);
    }
  }
  // ---- one-time: LDS fills ----
  {
    float4* e4 = (float4*)embS;
    const float4* we4 = (const float4*)w_emb;
    for (int idx = tid; idx < 2048; idx += NTHR) e4[idx] = we4[idx];
    if (tid < 256) e4[2048 + tid] = ((const float4*)g_emb)[tid];
    if (tid < 32) {
      int l = tid >> 4, r = tid & 15;
      int rw = (r >> 2) * HID + b * 4 + (r & 3);
      bsumS[l][r] = b_ih[l * 4096 + rw] + b_hh[l * 4096 + rw];
    }
    if (tid < 8) {
      int l = tid >> 2, jj = tid & 3;
      wsoftS[l][jj] = w_soft[l * HID + b * 4 + jj];
      cS[tid >> 2][tid & 3] = 0.0f;
    }
  }
  __syncthreads();

  auto dotW = [&](const float4* W, const float* v) -> float {
    float a = 0.0f;
#pragma unroll
    for (int i = 0; i < 8; ++i) {
      float4 x = *(const float4*)(v + col0 + i * 128);
      a = fmaf(W[i].x, x.x, a);
      a = fmaf(W[i].y, x.y, a);
      a = fmaf(W[i].z, x.z, a);
      a = fmaf(W[i].w, x.w, a);
    }
    return a;
  };

  auto gather = [&](unsigned epoch) {
    int ok;
    do {
      unsigned f = epoch;
      if (tid < NBLK)
        f = __hip_atomic_load(&flags[tid * 32], __ATOMIC_ACQUIRE,
                              __HIP_MEMORY_SCOPE_AGENT);
      ok = (f >= epoch);
    } while (!__syncthreads_and(ok));
  };

  int sample = 0;
  float accE = 0.0f, accLP = 0.0f;

  for (int s = 0; s < NSTEPS; ++s) {
    const int par = s & 1;

    // ---------------- layer 0 ----------------
    {
      const float* xsrc = embS + ((s == 0) ? 8 : sample) * HID;
      float r = dotW(Wih0, xsrc);
      if (s > 0) r += dotW(Whh0, h0buf + (par ^ 1) * HID);
#pragma unroll
      for (int m = 16; m >= 1; m >>= 1) r += __shfl_xor(r, m, 64);
      if (sub == 0) gatesS[row_idx] = r + bsumS[0][row_idx];
      __syncthreads();
      if (tid < 4) {
        float gi = gatesS[tid], gf = gatesS[4 + tid];
        float gg = gatesS[8 + tid], go = gatesS[12 + tid];
        float c = cS[0][tid];
        float cn = sigmoidf_(gf) * c + sigmoidf_(gi) * tanhf(gg);
        float hn = sigmoidf_(go) * tanhf(cn);
        cS[0][tid] = cn;
        h0buf[par * HID + b * 4 + tid] = hn;
      }
      __syncthreads();
    }
    // -------- barrier A: h0 visible grid-wide --------
    {
      const unsigned epochA = 2 * s + 1;
      if (tid == 0)
        __hip_atomic_store(&flags[b * 32], epochA, __ATOMIC_RELEASE,
                           __HIP_MEMORY_SCOPE_AGENT);
      if (b == 0) {
        gather(epochA);
        if (tid == 0)
          __hip_atomic_store(genA, epochA, __ATOMIC_RELEASE,
                             __HIP_MEMORY_SCOPE_AGENT);
      } else {
        if (tid == 0) {
          while (__hip_atomic_load(genA, __ATOMIC_ACQUIRE,
                                   __HIP_MEMORY_SCOPE_AGENT) < epochA)
            __builtin_amdgcn_s_sleep(1);
        }
        __syncthreads();
      }
    }

    // ---------------- layer 1 ----------------
    {
      float r = dotW(Wih1, h0buf + par * HID);
      if (s > 0) r += dotW(Whh1, h1buf + (par ^ 1) * HID);
#pragma unroll
      for (int m = 16; m >= 1; m >>= 1) r += __shfl_xor(r, m, 64);
      if (sub == 0) gatesS[row_idx] = r + bsumS[1][row_idx];
      __syncthreads();
      if (tid < 4) {
        float gi = gatesS[tid], gf = gatesS[4 + tid];
        float gg = gatesS[8 + tid], go = gatesS[12 + tid];
        float c = cS[1][tid];
        float cn = sigmoidf_(gf) * c + sigmoidf_(gi) * tanhf(gg);
        float hn = sigmoidf_(go) * tanhf(cn);
        cS[1][tid] = cn;
        h1buf[par * HID + b * 4 + tid] = hn;
        hS[tid] = hn;
      }
      __syncthreads();
      if (tid == 0) {
        float p0 = wsoftS[0][0] * hS[0] + wsoftS[0][1] * hS[1] +
                   wsoftS[0][2] * hS[2] + wsoftS[0][3] * hS[3];
        float p1 = wsoftS[1][0] * hS[0] + wsoftS[1][1] * hS[1] +
                   wsoftS[1][2] * hS[2] + wsoftS[1][3] * hS[3];
        part0[b] = p0;
        part1[b] = p1;
        __hip_atomic_store(&flags[b * 32], 2 * s + 2, __ATOMIC_RELEASE,
                           __HIP_MEMORY_SCOPE_AGENT);
      }
    }
    // -------- barrier B: block0 reduces logits, samples, broadcasts --------
    {
      const unsigned epochB = 2 * s + 2;
      if (b == 0) {
        gather(epochB);
        float v0 = (tid < NBLK) ? part0[tid] : 0.0f;
        float v1 = (tid < NBLK) ? part1[tid] : 0.0f;
#pragma unroll
        for (int m = 32; m >= 1; m >>= 1) {
          v0 += __shfl_xor(v0, m, 64);
          v1 += __shfl_xor(v1, m, 64);
        }
        if ((tid & 63) == 0) {
          wredS[0][tid >> 6] = v0;
          wredS[1][tid >> 6] = v1;
        }
        __syncthreads();
        if (tid == 0) {
          float t0 = wredS[0][0] + wredS[0][1] + wredS[0][2] + wredS[0][3];
          float t1 = wredS[1][0] + wredS[1][1] + wredS[1][2] + wredS[1][3];
          float l0 = 2.5f * tanhf(t0 / 5.0f);
          float l1 = 2.5f * tanhf(t1 / 5.0f);
          float m = fmaxf(l0, l1);
          float s0 = l0 - m, s1 = l1 - m;
          float lse = logf(expf(s0) + expf(s1));
          float lp0 = s0 - lse, lp1 = s1 - lse;
          // JAX partitionable threefry: subkey = tf((0,42),(0,s))
          uint32_t sk0, sk1, bt0, bt1, a, c;
          tf2x32(0u, 42u, 0u, (uint32_t)s, sk0, sk1);
          tf2x32(sk0, sk1, 0u, 0u, a, c); bt0 = a ^ c;
          tf2x32(sk0, sk1, 0u, 1u, a, c); bt1 = a ^ c;
          float gum0 = -logf(-logf(jax_uniform(bt0)));
          float gum1 = -logf(-logf(jax_uniform(bt1)));
          int smp = (gum1 + l1 > gum0 + l0) ? 1 : 0;
          accE += -(expf(lp0) * lp0 + expf(lp1) * lp1);
          accLP += smp ? lp1 : lp0;
          out[s] = (float)smp;
          sampS = smp;
          __hip_atomic_store(genB, (epochB << 1) | (unsigned)smp,
                             __ATOMIC_RELEASE, __HIP_MEMORY_SCOPE_AGENT);
        }
        __syncthreads();
        sample = sampS;
      } else {
        if (tid == 0) {
          unsigned v;
          while (((v = __hip_atomic_load(genB, __ATOMIC_ACQUIRE,
                                         __HIP_MEMORY_SCOPE_AGENT)) >> 1) < epochB)
            __builtin_amdgcn_s_sleep(1);
          sampS = (int)(v & 1u);
        }
        __syncthreads();
        sample = sampS;
      }
    }
  }

  if (b == 0 && tid == 0) {
    out[96] = accE;
    out[97] = accLP;
  }
}

extern "C" void kernel_launch(void* const* d_in, const int* in_sizes, int n_in,
                              void* d_out, int out_size, void* d_ws, size_t ws_size,
                              hipStream_t stream) {
  const float* g_emb = (const float*)d_in[0];
  const float* w_emb = (const float*)d_in[1];
  const float* w_soft = (const float*)d_in[2];
  const float* w_ih = (const float*)d_in[3];
  const float* w_hh = (const float*)d_in[4];
  const float* b_ih = (const float*)d_in[5];
  const float* b_hh = (const float*)d_in[6];
  float* out = (float*)d_out;
  float* ws = (float*)d_ws;

  // flags/gens/h-buffers must start zeroed (harness poisons ws with 0xAA)
  hipMemsetAsync(ws, 0, WS_TOTAL * sizeof(float), stream);

  enas_controller<<<dim3(NBLK), dim3(NTHR), 0, stream>>>(
      g_emb, w_emb, w_soft, w_ih, w_hh, b_ih, b_hh, out, ws);
}

// Round 4
// 2422.934 us; speedup vs baseline: 2.7793x; 1.8654x over previous
//
#include <hip/hip_runtime.h>
#include <cstdint>
#include <cstddef>

#define NSTEPS 96
#define HID 1024
#define NBLK 256
#define NTHR 512

// ws float offsets. Double-buffered exchange: BUF(p) = p*3584
//   H1OFF  +0    : [1024]  h1[k]
//   H0COFF +1024 : [2][1024] h0[k+1] candidates (by sample value)
//   POFF   +3072 : [2][256]  per-block partial logits of h1[k]
#define BUFSZ 3584
#define H1OFF 0
#define H0COFF 1024
#define POFF 3072
#define WS_FLAGS 7168         // 256 flags, stride 32 floats (128B)
#define WS_TOTAL 15360

// ---------------- Threefry-2x32-20 (exact JAX algorithm) ----------------
__device__ __forceinline__ void tf2x32(uint32_t k0, uint32_t k1,
                                       uint32_t x0, uint32_t x1,
                                       uint32_t& o0, uint32_t& o1) {
  uint32_t ks[3] = {k0, k1, k0 ^ k1 ^ 0x1BD11BDAu};
  x0 += ks[0];
  x1 += ks[1];
  const uint32_t R[2][4] = {{13u, 15u, 26u, 6u}, {17u, 29u, 16u, 24u}};
#pragma unroll
  for (int i = 0; i < 5; ++i) {
#pragma unroll
    for (int r = 0; r < 4; ++r) {
      uint32_t rot = R[i & 1][r];
      x0 += x1;
      x1 = (x1 << rot) | (x1 >> (32u - rot));
      x1 ^= x0;
    }
    x0 += ks[(i + 1) % 3];
    x1 += ks[(i + 2) % 3] + (uint32_t)(i + 1);
  }
  o0 = x0;
  o1 = x1;
}

__device__ __forceinline__ float jax_uniform(uint32_t bits) {
  const float TINY = 1.17549435e-38f;
  float f = __uint_as_float((bits >> 9) | 0x3f800000u) - 1.0f;
  f = f * (1.0f - TINY) + TINY;
  return fmaxf(TINY, f);
}

__device__ __forceinline__ float sigmoidf_(float x) {
  return 1.0f / (1.0f + expf(-x));
}

// 256 blocks x 512 threads; block b owns hidden units [4b,4b+4) of both
// layers. Thread = (row_idx=tid>>5, sub=tid&31), cols col0=sub*4 + i*128.
// Register-resident: W_ih1, W_hh1, W_hh0 row slices (24 float4). W_ih0 is
// FOLDED AWAY: its input is always one of {emb0, emb1, g_emb}, so the 16
// per-block x-dots are precomputed once into LDS. Per step, each block emits
// BOTH h0[k+1] candidates (sample=0/1); readers select after redundantly
// computing sample[k]. => ONE flat grid barrier per step.
__global__ void __launch_bounds__(NTHR, 1)
enas_controller(const float* __restrict__ g_emb,   // [1,1024]
                const float* __restrict__ w_emb,   // [8,1024]
                const float* __restrict__ w_soft,  // [2,1024]
                const float* __restrict__ w_ih,    // [2,4096,1024]
                const float* __restrict__ w_hh,    // [2,4096,1024]
                const float* __restrict__ b_ih,    // [2,4096]
                const float* __restrict__ b_hh,    // [2,4096]
                float* __restrict__ out,           // [98]
                float* __restrict__ ws) {          // >= WS_TOTAL floats, zeroed
  const int tid = threadIdx.x;
  const int b = blockIdx.x;
  const int row_idx = tid >> 5;
  const int sub = tid & 31;
  const int q = row_idx >> 2;
  const int j = row_idx & 3;
  const int row = q * HID + (b * 4 + j);  // gate row within one layer's 4096
  const int col0 = sub * 4;               // + i*128 interleave

  unsigned* flags = (unsigned*)(ws + WS_FLAGS);

  __shared__ float xdotPre[16][3];  // [gate row][x in {emb0, emb1, g_emb}]
  __shared__ float bsumS[2][16];
  __shared__ float wsoftS[2][4];
  __shared__ float gatesS[16];      // layer-1 gate sums
  __shared__ float hdotS[16];       // W_hh0 @ h0  per gate row
  __shared__ float cS1[4];
  __shared__ float c0cand[2][4];
  __shared__ float hS[4];
  __shared__ float wredS[2][8];
  __shared__ int sampS;

  // ---- one-time: weights into registers ----
  float4 Wih1[8], Whh1[8], Whh0[8];
  {
    const float* p_ih1 = w_ih + (size_t)(4096 + row) * HID;
    const float* p_hh0 = w_hh + (size_t)row * HID;
    const float* p_hh1 = w_hh + (size_t)(4096 + row) * HID;
#pragma unroll
    for (int i = 0; i < 8; ++i) {
      Wih1[i] = *(const float4*)(p_ih1 + col0 + i * 128);
      Whh0[i] = *(const float4*)(p_hh0 + col0 + i * 128);
      Whh1[i] = *(const float4*)(p_hh1 + col0 + i * 128);
    }
  }
  // ---- one-time: fold W_ih0 against the 3 possible inputs ----
  {
    const float* p_ih0 = w_ih + (size_t)row * HID;
    const float* xs[3] = {w_emb, w_emb + HID, g_emb};
#pragma unroll
    for (int vi = 0; vi < 3; ++vi) {
      float a = 0.0f;
#pragma unroll
      for (int i = 0; i < 8; ++i) {
        float4 wv = *(const float4*)(p_ih0 + col0 + i * 128);
        float4 xv = *(const float4*)(xs[vi] + col0 + i * 128);
        a = fmaf(wv.x, xv.x, a); a = fmaf(wv.y, xv.y, a);
        a = fmaf(wv.z, xv.z, a); a = fmaf(wv.w, xv.w, a);
      }
#pragma unroll
      for (int m = 16; m >= 1; m >>= 1) a += __shfl_xor(a, m, 64);
      if (sub == 0) xdotPre[row_idx][vi] = a;
    }
    if (tid < 32) {
      int l = tid >> 4, r = tid & 15;
      int rw = (r >> 2) * HID + b * 4 + (r & 3);
      bsumS[l][r] = b_ih[l * 4096 + rw] + b_hh[l * 4096 + rw];
    }
    if (tid < 8) wsoftS[tid >> 2][tid & 3] = w_soft[(tid >> 2) * HID + b * 4 + (tid & 3)];
    if (tid < 4) cS1[tid] = 0.0f;
  }
  __syncthreads();

  // ---- pre-loop: h0[0] = LSTM0(g_emb, h=0, c=0); publish into BUF(0) ----
  {
    float* bufW = ws;  // BUF(0)
    if (tid < 4) {
      float gi = xdotPre[tid][2] + bsumS[0][tid];
      float gf = xdotPre[4 + tid][2] + bsumS[0][4 + tid];
      float gg = xdotPre[8 + tid][2] + bsumS[0][8 + tid];
      float go = xdotPre[12 + tid][2] + bsumS[0][12 + tid];
      float cn = sigmoidf_(gi) * tanhf(gg);        // c=0 -> f-term vanishes
      float hn = sigmoidf_(go) * tanhf(cn);
      c0cand[0][tid] = cn;
      c0cand[1][tid] = cn;
      bufW[H0COFF + b * 4 + tid] = hn;
      bufW[H0COFF + HID + b * 4 + tid] = hn;
    }
    __syncthreads();
    if (tid == 0)
      __hip_atomic_store(&flags[b * 32], 1u, __ATOMIC_RELEASE,
                         __HIP_MEMORY_SCOPE_AGENT);
  }

  float accE = 0.0f, accLP = 0.0f;

  for (int k = 0; k <= NSTEPS; ++k) {
    // ---- flat one-hop barrier: wait for all flags >= k+1 ----
    {
      const unsigned e = (unsigned)(k + 1);
      int ok;
      do {
        unsigned f = e;
        if (tid < NBLK)
          f = __hip_atomic_load(&flags[tid * 32], __ATOMIC_RELAXED,
                                __HIP_MEMORY_SCOPE_AGENT);
        ok = (f >= e);
      } while (!__syncthreads_and(ok));
      // one acquire to invalidate stale cache lines before data reads
      (void)__hip_atomic_load(&flags[b * 32], __ATOMIC_ACQUIRE,
                              __HIP_MEMORY_SCOPE_AGENT);
      __syncthreads();
    }

    const float* bufR = ws + (size_t)(k & 1) * BUFSZ;
    float* bufW = ws + (size_t)((k + 1) & 1) * BUFSZ;

    // ---- sample[k-1]: redundant, bit-identical in every block ----
    int smp = 0;
    if (k > 0) {
      float v0 = 0.0f, v1 = 0.0f;
      if (tid < NBLK) {
        v0 = bufR[POFF + tid];
        v1 = bufR[POFF + NBLK + tid];
      }
#pragma unroll
      for (int m = 32; m >= 1; m >>= 1) {
        v0 += __shfl_xor(v0, m, 64);
        v1 += __shfl_xor(v1, m, 64);
      }
      if ((tid & 63) == 0) {
        wredS[0][tid >> 6] = v0;
        wredS[1][tid >> 6] = v1;
      }
      __syncthreads();
      if (tid == 0) {
        float t0 = ((wredS[0][0] + wredS[0][1]) + (wredS[0][2] + wredS[0][3])) +
                   ((wredS[0][4] + wredS[0][5]) + (wredS[0][6] + wredS[0][7]));
        float t1 = ((wredS[1][0] + wredS[1][1]) + (wredS[1][2] + wredS[1][3])) +
                   ((wredS[1][4] + wredS[1][5]) + (wredS[1][6] + wredS[1][7]));
        float l0 = 2.5f * tanhf(t0 / 5.0f);
        float l1 = 2.5f * tanhf(t1 / 5.0f);
        float m = fmaxf(l0, l1);
        float s0 = l0 - m, s1 = l1 - m;
        float lse = logf(expf(s0) + expf(s1));
        float lp0 = s0 - lse, lp1 = s1 - lse;
        uint32_t sk0, sk1, bt0, bt1, a, c;
        tf2x32(0u, 42u, 0u, (uint32_t)(k - 1), sk0, sk1);
        tf2x32(sk0, sk1, 0u, 0u, a, c); bt0 = a ^ c;
        tf2x32(sk0, sk1, 0u, 1u, a, c); bt1 = a ^ c;
        float gum0 = -logf(-logf(jax_uniform(bt0)));
        float gum1 = -logf(-logf(jax_uniform(bt1)));
        int sm = (gum1 + l1 > gum0 + l0) ? 1 : 0;
        accE += -(expf(lp0) * lp0 + expf(lp1) * lp1);
        accLP += sm ? lp1 : lp0;
        sampS = sm;
        if (b == 0) out[k - 1] = (float)sm;
      }
      __syncthreads();
      smp = sampS;
    }
    if (k == NSTEPS) break;

    // ---- fused compute: layer1(h0[k], h1[k-1]) and W_hh0 @ h0[k] ----
    const float* h0v = bufR + H0COFF + (size_t)smp * HID;
    const float* h1v = bufR + H1OFF;

    float a1 = 0.0f, a0 = 0.0f;
#pragma unroll
    for (int i = 0; i < 8; ++i) {
      float4 x = *(const float4*)(h0v + col0 + i * 128);
      a1 = fmaf(Wih1[i].x, x.x, a1); a1 = fmaf(Wih1[i].y, x.y, a1);
      a1 = fmaf(Wih1[i].z, x.z, a1); a1 = fmaf(Wih1[i].w, x.w, a1);
      a0 = fmaf(Whh0[i].x, x.x, a0); a0 = fmaf(Whh0[i].y, x.y, a0);
      a0 = fmaf(Whh0[i].z, x.z, a0); a0 = fmaf(Whh0[i].w, x.w, a0);
    }
    if (k > 0) {
#pragma unroll
      for (int i = 0; i < 8; ++i) {
        float4 h = *(const float4*)(h1v + col0 + i * 128);
        a1 = fmaf(Whh1[i].x, h.x, a1); a1 = fmaf(Whh1[i].y, h.y, a1);
        a1 = fmaf(Whh1[i].z, h.z, a1); a1 = fmaf(Whh1[i].w, h.w, a1);
      }
    }
#pragma unroll
    for (int m = 16; m >= 1; m >>= 1) {
      a1 += __shfl_xor(a1, m, 64);
      a0 += __shfl_xor(a0, m, 64);
    }
    if (sub == 0) {
      gatesS[row_idx] = a1 + bsumS[1][row_idx];
      hdotS[row_idx] = a0;
    }
    __syncthreads();

    if (tid < 4) {
      // layer-1 cell -> h1[k] own units
      {
        float gi = gatesS[tid], gf = gatesS[4 + tid];
        float gg = gatesS[8 + tid], go = gatesS[12 + tid];
        float c = cS1[tid];
        float cn = sigmoidf_(gf) * c + sigmoidf_(gi) * tanhf(gg);
        float hn = sigmoidf_(go) * tanhf(cn);
        cS1[tid] = cn;
        hS[tid] = hn;
        bufW[H1OFF + b * 4 + tid] = hn;
      }
      // layer-0 dual candidates for h0[k+1]
      float c0sel = c0cand[smp][tid];
#pragma unroll
      for (int jj = 0; jj < 2; ++jj) {
        float gi = xdotPre[tid][jj] + hdotS[tid] + bsumS[0][tid];
        float gf = xdotPre[4 + tid][jj] + hdotS[4 + tid] + bsumS[0][4 + tid];
        float gg = xdotPre[8 + tid][jj] + hdotS[8 + tid] + bsumS[0][8 + tid];
        float go = xdotPre[12 + tid][jj] + hdotS[12 + tid] + bsumS[0][12 + tid];
        float cn = sigmoidf_(gf) * c0sel + sigmoidf_(gi) * tanhf(gg);
        float hn = sigmoidf_(go) * tanhf(cn);
        c0cand[jj][tid] = cn;
        bufW[H0COFF + (size_t)jj * HID + b * 4 + tid] = hn;
      }
    }
    __syncthreads();
    if (tid == 0) {
      float p0 = wsoftS[0][0] * hS[0] + wsoftS[0][1] * hS[1] +
                 wsoftS[0][2] * hS[2] + wsoftS[0][3] * hS[3];
      float p1 = wsoftS[1][0] * hS[0] + wsoftS[1][1] * hS[1] +
                 wsoftS[1][2] * hS[2] + wsoftS[1][3] * hS[3];
      bufW[POFF + b] = p0;
      bufW[POFF + NBLK + b] = p1;
      __hip_atomic_store(&flags[b * 32], (unsigned)(k + 2), __ATOMIC_RELEASE,
                         __HIP_MEMORY_SCOPE_AGENT);
    }
  }

  if (b == 0 && tid == 0) {
    out[96] = accE;
    out[97] = accLP;
  }
}

extern "C" void kernel_launch(void* const* d_in, const int* in_sizes, int n_in,
                              void* d_out, int out_size, void* d_ws, size_t ws_size,
                              hipStream_t stream) {
  const float* g_emb = (const float*)d_in[0];
  const float* w_emb = (const float*)d_in[1];
  const float* w_soft = (const float*)d_in[2];
  const float* w_ih = (const float*)d_in[3];
  const float* w_hh = (const float*)d_in[4];
  const float* b_ih = (const float*)d_in[5];
  const float* b_hh = (const float*)d_in[6];
  float* out = (float*)d_out;
  float* ws = (float*)d_ws;

  // flags + exchange buffers must start zeroed (harness poisons ws with 0xAA)
  hipMemsetAsync(ws, 0, WS_TOTAL * sizeof(float), stream);

  enas_controller<<<dim3(NBLK), dim3(NTHR), 0, stream>>>(
      g_emb, w_emb, w_soft, w_ih, w_hh, b_ih, b_hh, out, ws);
}

// Round 5
// 2395.504 us; speedup vs baseline: 2.8111x; 1.0115x over previous
//
#include <hip/hip_runtime.h>
#include <cstdint>
#include <cstddef>

#define NSTEPS 96
#define HID 1024
#define NBLK 256
#define NTHR 512

// ws float offsets. Double-buffered exchange: BUF(p) = p*3584
//   H1OFF  +0    : [1024]  h1[k]
//   H0COFF +1024 : [2][1024] h0[k+1] candidates (by sample value)
//   POFF   +3072 : [2][256]  per-block partial logits of h1[k]
#define BUFSZ 3584
#define H1OFF 0
#define H0COFF 1024
#define POFF 3072
#define WS_FLAGS 7168         // 256 flags, stride 32 floats (128B)
#define WS_TOTAL 15360

// Opaque register pin: value becomes asm-defined -> cannot be rematerialized
// from memory, must stay live in VGPRs across the step loop.
#define PIN4(v) asm volatile("" : "+v"(v.x), "+v"(v.y), "+v"(v.z), "+v"(v.w))

// ---------------- Threefry-2x32-20 (exact JAX algorithm) ----------------
__device__ __forceinline__ void tf2x32(uint32_t k0, uint32_t k1,
                                       uint32_t x0, uint32_t x1,
                                       uint32_t& o0, uint32_t& o1) {
  uint32_t ks[3] = {k0, k1, k0 ^ k1 ^ 0x1BD11BDAu};
  x0 += ks[0];
  x1 += ks[1];
  const uint32_t R[2][4] = {{13u, 15u, 26u, 6u}, {17u, 29u, 16u, 24u}};
#pragma unroll
  for (int i = 0; i < 5; ++i) {
#pragma unroll
    for (int r = 0; r < 4; ++r) {
      uint32_t rot = R[i & 1][r];
      x0 += x1;
      x1 = (x1 << rot) | (x1 >> (32u - rot));
      x1 ^= x0;
    }
    x0 += ks[(i + 1) % 3];
    x1 += ks[(i + 2) % 3] + (uint32_t)(i + 1);
  }
  o0 = x0;
  o1 = x1;
}

__device__ __forceinline__ float jax_uniform(uint32_t bits) {
  const float TINY = 1.17549435e-38f;
  float f = __uint_as_float((bits >> 9) | 0x3f800000u) - 1.0f;
  f = f * (1.0f - TINY) + TINY;
  return fmaxf(TINY, f);
}

__device__ __forceinline__ float sigmoidf_(float x) {
  return 1.0f / (1.0f + expf(-x));
}

// 256 blocks x 512 threads; block b owns hidden units [4b,4b+4) of both
// layers. Thread = (row_idx=tid>>5, sub=tid&31), cols col0=sub*4 + i*128.
// W_ih1/W_hh1/W_hh0 row slices PINNED in VGPRs (24 float4). W_ih0 folded
// away against its 3 possible inputs. Per step each block publishes h1[k],
// both h0[k+1] candidates, and partial logits; ONE flat grid barrier/step.
// All 5 dot passes are sample-independent and issue before the sample
// reduction completes (latency overlap); selection is a uniform cndmask.
__global__ void __launch_bounds__(NTHR, 1)
enas_controller(const float* __restrict__ g_emb,   // [1,1024]
                const float* __restrict__ w_emb,   // [8,1024]
                const float* __restrict__ w_soft,  // [2,1024]
                const float* __restrict__ w_ih,    // [2,4096,1024]
                const float* __restrict__ w_hh,    // [2,4096,1024]
                const float* __restrict__ b_ih,    // [2,4096]
                const float* __restrict__ b_hh,    // [2,4096]
                float* __restrict__ out,           // [98]
                float* __restrict__ ws) {          // >= WS_TOTAL floats, zeroed
  const int tid = threadIdx.x;
  const int b = blockIdx.x;
  const int row_idx = tid >> 5;
  const int sub = tid & 31;
  const int q = row_idx >> 2;
  const int j = row_idx & 3;
  const int row = q * HID + (b * 4 + j);  // gate row within one layer's 4096
  const int col0 = sub * 4;               // + i*128 interleave

  unsigned* flags = (unsigned*)(ws + WS_FLAGS);

  __shared__ float xdotPre[16][3];  // [gate row][x in {emb0, emb1, g_emb}]
  __shared__ float bsumS[2][16];
  __shared__ float wsoftS[2][4];
  __shared__ float gatesS[16];      // layer-1 gate sums
  __shared__ float hdotS[16];       // W_hh0 @ h0  per gate row
  __shared__ float cS1[4];
  __shared__ float c0cand[2][4];
  __shared__ float hS[4];
  __shared__ float wredS[2][8];
  __shared__ int sampS;

  // ---- one-time: weights into registers (then PINNED) ----
  float4 Wih1[8], Whh1[8], Whh0[8];
  {
    const float* p_ih1 = w_ih + (size_t)(4096 + row) * HID;
    const float* p_hh0 = w_hh + (size_t)row * HID;
    const float* p_hh1 = w_hh + (size_t)(4096 + row) * HID;
#pragma unroll
    for (int i = 0; i < 8; ++i) {
      Wih1[i] = *(const float4*)(p_ih1 + col0 + i * 128);
      Whh0[i] = *(const float4*)(p_hh0 + col0 + i * 128);
      Whh1[i] = *(const float4*)(p_hh1 + col0 + i * 128);
    }
#pragma unroll
    for (int i = 0; i < 8; ++i) { PIN4(Wih1[i]); PIN4(Whh0[i]); PIN4(Whh1[i]); }
  }
  // ---- one-time: fold W_ih0 against the 3 possible inputs ----
  {
    const float* p_ih0 = w_ih + (size_t)row * HID;
    const float* xs[3] = {w_emb, w_emb + HID, g_emb};
#pragma unroll
    for (int vi = 0; vi < 3; ++vi) {
      float a = 0.0f;
#pragma unroll
      for (int i = 0; i < 8; ++i) {
        float4 wv = *(const float4*)(p_ih0 + col0 + i * 128);
        float4 xv = *(const float4*)(xs[vi] + col0 + i * 128);
        a = fmaf(wv.x, xv.x, a); a = fmaf(wv.y, xv.y, a);
        a = fmaf(wv.z, xv.z, a); a = fmaf(wv.w, xv.w, a);
      }
#pragma unroll
      for (int m = 16; m >= 1; m >>= 1) a += __shfl_xor(a, m, 64);
      if (sub == 0) xdotPre[row_idx][vi] = a;
    }
    if (tid < 32) {
      int l = tid >> 4, r = tid & 15;
      int rw = (r >> 2) * HID + b * 4 + (r & 3);
      bsumS[l][r] = b_ih[l * 4096 + rw] + b_hh[l * 4096 + rw];
    }
    if (tid < 8) wsoftS[tid >> 2][tid & 3] = w_soft[(tid >> 2) * HID + b * 4 + (tid & 3)];
    if (tid < 4) cS1[tid] = 0.0f;
  }
  __syncthreads();

  // ---- pre-loop: h0[0] = LSTM0(g_emb, h=0, c=0); publish into BUF(0) ----
  {
    float* bufW = ws;  // BUF(0)
    if (tid < 4) {
      float gi = xdotPre[tid][2] + bsumS[0][tid];
      float gg = xdotPre[8 + tid][2] + bsumS[0][8 + tid];
      float go = xdotPre[12 + tid][2] + bsumS[0][12 + tid];
      float cn = sigmoidf_(gi) * tanhf(gg);        // c=0 -> f-term vanishes
      float hn = sigmoidf_(go) * tanhf(cn);
      c0cand[0][tid] = cn;
      c0cand[1][tid] = cn;
      bufW[H0COFF + b * 4 + tid] = hn;
      bufW[H0COFF + HID + b * 4 + tid] = hn;
    }
    __syncthreads();
    if (tid == 0)
      __hip_atomic_store(&flags[b * 32], 1u, __ATOMIC_RELEASE,
                         __HIP_MEMORY_SCOPE_AGENT);
  }

  float accE = 0.0f, accLP = 0.0f;

  for (int k = 0; k <= NSTEPS; ++k) {
    // ---- flat one-hop barrier: wait for all flags >= k+1 ----
    {
      const unsigned e = (unsigned)(k + 1);
      int ok;
      do {
        unsigned f = e;
        if (tid < NBLK)
          f = __hip_atomic_load(&flags[tid * 32], __ATOMIC_RELAXED,
                                __HIP_MEMORY_SCOPE_AGENT);
        ok = (f >= e);
      } while (!__syncthreads_and(ok));
      // per-thread acquire: orders this thread's subsequent data reads
      (void)__hip_atomic_load(&flags[b * 32], __ATOMIC_ACQUIRE,
                              __HIP_MEMORY_SCOPE_AGENT);
    }

    const float* bufR = ws + (size_t)(k & 1) * BUFSZ;
    float* bufW = ws + (size_t)((k + 1) & 1) * BUFSZ;

    // ---- 5 sample-independent dot passes: issue loads NOW (overlap with
    //      the sample reduction below). At k==0 h1 region is exact zeros.
    const float* h0c0 = bufR + H0COFF;
    const float* h0c1 = bufR + H0COFF + HID;
    const float* h1v = bufR + H1OFF;
    float aW1c0 = 0.0f, aW1c1 = 0.0f, aH0c0 = 0.0f, aH0c1 = 0.0f, aHH1 = 0.0f;
#pragma unroll
    for (int i = 0; i < 8; ++i) {
      float4 x0 = *(const float4*)(h0c0 + col0 + i * 128);
      float4 x1 = *(const float4*)(h0c1 + col0 + i * 128);
      float4 hh = *(const float4*)(h1v + col0 + i * 128);
      aW1c0 = fmaf(Wih1[i].x, x0.x, aW1c0); aW1c0 = fmaf(Wih1[i].y, x0.y, aW1c0);
      aW1c0 = fmaf(Wih1[i].z, x0.z, aW1c0); aW1c0 = fmaf(Wih1[i].w, x0.w, aW1c0);
      aW1c1 = fmaf(Wih1[i].x, x1.x, aW1c1); aW1c1 = fmaf(Wih1[i].y, x1.y, aW1c1);
      aW1c1 = fmaf(Wih1[i].z, x1.z, aW1c1); aW1c1 = fmaf(Wih1[i].w, x1.w, aW1c1);
      aH0c0 = fmaf(Whh0[i].x, x0.x, aH0c0); aH0c0 = fmaf(Whh0[i].y, x0.y, aH0c0);
      aH0c0 = fmaf(Whh0[i].z, x0.z, aH0c0); aH0c0 = fmaf(Whh0[i].w, x0.w, aH0c0);
      aH0c1 = fmaf(Whh0[i].x, x1.x, aH0c1); aH0c1 = fmaf(Whh0[i].y, x1.y, aH0c1);
      aH0c1 = fmaf(Whh0[i].z, x1.z, aH0c1); aH0c1 = fmaf(Whh0[i].w, x1.w, aH0c1);
      aHH1 = fmaf(Whh1[i].x, hh.x, aHH1); aHH1 = fmaf(Whh1[i].y, hh.y, aHH1);
      aHH1 = fmaf(Whh1[i].z, hh.z, aHH1); aHH1 = fmaf(Whh1[i].w, hh.w, aHH1);
    }

    // ---- sample[k-1]: redundant, bit-identical in every block ----
    int smp = 0;
    if (k > 0) {
      float v0 = 0.0f, v1 = 0.0f;
      if (tid < NBLK) {
        v0 = bufR[POFF + tid];
        v1 = bufR[POFF + NBLK + tid];
      }
#pragma unroll
      for (int m = 32; m >= 1; m >>= 1) {
        v0 += __shfl_xor(v0, m, 64);
        v1 += __shfl_xor(v1, m, 64);
      }
      if ((tid & 63) == 0) {
        wredS[0][tid >> 6] = v0;
        wredS[1][tid >> 6] = v1;
      }
      __syncthreads();
      if (tid == 0) {
        float t0 = ((wredS[0][0] + wredS[0][1]) + (wredS[0][2] + wredS[0][3])) +
                   ((wredS[0][4] + wredS[0][5]) + (wredS[0][6] + wredS[0][7]));
        float t1 = ((wredS[1][0] + wredS[1][1]) + (wredS[1][2] + wredS[1][3])) +
                   ((wredS[1][4] + wredS[1][5]) + (wredS[1][6] + wredS[1][7]));
        float l0 = 2.5f * tanhf(t0 / 5.0f);
        float l1 = 2.5f * tanhf(t1 / 5.0f);
        float m = fmaxf(l0, l1);
        float s0 = l0 - m, s1 = l1 - m;
        float lse = logf(expf(s0) + expf(s1));
        float lp0 = s0 - lse, lp1 = s1 - lse;
        uint32_t sk0, sk1, bt0, bt1, a, c;
        tf2x32(0u, 42u, 0u, (uint32_t)(k - 1), sk0, sk1);
        tf2x32(sk0, sk1, 0u, 0u, a, c); bt0 = a ^ c;
        tf2x32(sk0, sk1, 0u, 1u, a, c); bt1 = a ^ c;
        float gum0 = -logf(-logf(jax_uniform(bt0)));
        float gum1 = -logf(-logf(jax_uniform(bt1)));
        int sm = (gum1 + l1 > gum0 + l0) ? 1 : 0;
        accE += -(expf(lp0) * lp0 + expf(lp1) * lp1);
        accLP += sm ? lp1 : lp0;
        sampS = sm;
        if (b == 0) out[k - 1] = (float)sm;
      }
      __syncthreads();
      smp = sampS;
    }
    if (k == NSTEPS) break;

    // ---- select candidate (uniform cndmask) and reduce ----
    float a1 = (smp ? aW1c1 : aW1c0) + aHH1;
    float a0 = smp ? aH0c1 : aH0c0;
#pragma unroll
    for (int m = 16; m >= 1; m >>= 1) {
      a1 += __shfl_xor(a1, m, 64);
      a0 += __shfl_xor(a0, m, 64);
    }
    if (sub == 0) {
      gatesS[row_idx] = a1 + bsumS[1][row_idx];
      hdotS[row_idx] = a0;
    }
    __syncthreads();

    if (tid < 4) {
      // layer-1 cell -> h1[k] own units
      {
        float gi = gatesS[tid], gf = gatesS[4 + tid];
        float gg = gatesS[8 + tid], go = gatesS[12 + tid];
        float c = cS1[tid];
        float cn = sigmoidf_(gf) * c + sigmoidf_(gi) * tanhf(gg);
        float hn = sigmoidf_(go) * tanhf(cn);
        cS1[tid] = cn;
        hS[tid] = hn;
        bufW[H1OFF + b * 4 + tid] = hn;
      }
      // layer-0 dual candidates for h0[k+1]
      float c0sel = c0cand[smp][tid];
#pragma unroll
      for (int jj = 0; jj < 2; ++jj) {
        float gi = xdotPre[tid][jj] + hdotS[tid] + bsumS[0][tid];
        float gf = xdotPre[4 + tid][jj] + hdotS[4 + tid] + bsumS[0][4 + tid];
        float gg = xdotPre[8 + tid][jj] + hdotS[8 + tid] + bsumS[0][8 + tid];
        float go = xdotPre[12 + tid][jj] + hdotS[12 + tid] + bsumS[0][12 + tid];
        float cn = sigmoidf_(gf) * c0sel + sigmoidf_(gi) * tanhf(gg);
        float hn = sigmoidf_(go) * tanhf(cn);
        c0cand[jj][tid] = cn;
        bufW[H0COFF + (size_t)jj * HID + b * 4 + tid] = hn;
      }
    }
    __syncthreads();
    if (tid == 0) {
      float p0 = wsoftS[0][0] * hS[0] + wsoftS[0][1] * hS[1] +
                 wsoftS[0][2] * hS[2] + wsoftS[0][3] * hS[3];
      float p1 = wsoftS[1][0] * hS[0] + wsoftS[1][1] * hS[1] +
                 wsoftS[1][2] * hS[2] + wsoftS[1][3] * hS[3];
      bufW[POFF + b] = p0;
      bufW[POFF + NBLK + b] = p1;
      __hip_atomic_store(&flags[b * 32], (unsigned)(k + 2), __ATOMIC_RELEASE,
                         __HIP_MEMORY_SCOPE_AGENT);
    }
  }

  if (b == 0 && tid == 0) {
    out[96] = accE;
    out[97] = accLP;
  }
}

extern "C" void kernel_launch(void* const* d_in, const int* in_sizes, int n_in,
                              void* d_out, int out_size, void* d_ws, size_t ws_size,
                              hipStream_t stream) {
  const float* g_emb = (const float*)d_in[0];
  const float* w_emb = (const float*)d_in[1];
  const float* w_soft = (const float*)d_in[2];
  const float* w_ih = (const float*)d_in[3];
  const float* w_hh = (const float*)d_in[4];
  const float* b_ih = (const float*)d_in[5];
  const float* b_hh = (const float*)d_in[6];
  float* out = (float*)d_out;
  float* ws = (float*)d_ws;

  // flags + exchange buffers must start zeroed (harness poisons ws with 0xAA)
  hipMemsetAsync(ws, 0, WS_TOTAL * sizeof(float), stream);

  enas_controller<<<dim3(NBLK), dim3(NTHR), 0, stream>>>(
      g_emb, w_emb, w_soft, w_ih, w_hh, b_ih, b_hh, out, ws);
}

// Round 7
// 716.596 us; speedup vs baseline: 9.3972x; 3.3429x over previous
//
#include <hip/hip_runtime.h>
#include <cstdint>
#include <cstddef>

#define NSTEPS 96
#define HID 1024
#define NBLK 256
#define NTHR 512

// ws float offsets. Double-buffered exchange: BUF(p) = p*3584
//   +0    : [1024]    h1[k]
//   +1024 : [2][1024] h0[k+1] candidates (by sample value)
//   +3072 : [2][256]  per-block partial logits of h1[k]
#define BUFSZ 3584
#define H1OFF 0
#define H0COFF 1024
#define POFF 3072
#define WS_FLAGS 7168         // 256 flags, stride 32 floats (128B)
#define WS_TOTAL 15360

// Opaque register pin: value becomes asm-defined -> cannot be rematerialized
// from memory, must stay live in VGPRs across the step loop.
#define PIN4(v) asm volatile("" : "+v"(v.x), "+v"(v.y), "+v"(v.z), "+v"(v.w))

// Relaxed agent-scope ops: plain global_load/store with sc1 (LLC, the
// coherence point) and NO buffer_wbl2/buffer_inv cache maintenance.
__device__ __forceinline__ float ld_llc(const float* p) {
  return __hip_atomic_load(p, __ATOMIC_RELAXED, __HIP_MEMORY_SCOPE_AGENT);
}
__device__ __forceinline__ void st_llc(float* p, float v) {
  __hip_atomic_store(p, v, __ATOMIC_RELAXED, __HIP_MEMORY_SCOPE_AGENT);
}

// ---------------- Threefry-2x32-20 (exact JAX algorithm) ----------------
__device__ __forceinline__ void tf2x32(uint32_t k0, uint32_t k1,
                                       uint32_t x0, uint32_t x1,
                                       uint32_t& o0, uint32_t& o1) {
  uint32_t ks[3] = {k0, k1, k0 ^ k1 ^ 0x1BD11BDAu};
  x0 += ks[0];
  x1 += ks[1];
  const uint32_t R[2][4] = {{13u, 15u, 26u, 6u}, {17u, 29u, 16u, 24u}};
#pragma unroll
  for (int i = 0; i < 5; ++i) {
#pragma unroll
    for (int r = 0; r < 4; ++r) {
      uint32_t rot = R[i & 1][r];
      x0 += x1;
      x1 = (x1 << rot) | (x1 >> (32u - rot));
      x1 ^= x0;
    }
    x0 += ks[(i + 1) % 3];
    x1 += ks[(i + 2) % 3] + (uint32_t)(i + 1);
  }
  o0 = x0;
  o1 = x1;
}

__device__ __forceinline__ float jax_uniform(uint32_t bits) {
  const float TINY = 1.17549435e-38f;
  float f = __uint_as_float((bits >> 9) | 0x3f800000u) - 1.0f;
  f = f * (1.0f - TINY) + TINY;
  return fmaxf(TINY, f);
}

__device__ __forceinline__ float sigmoidf_(float x) {
  return 1.0f / (1.0f + expf(-x));
}

// 256 blocks x 512 threads; block b owns hidden units [4b,4b+4) of both
// layers. W_ih1/W_hh1/W_hh0 row slices pinned in VGPRs; W_ih0 folded away.
// ONE flat grid barrier per step built purely from relaxed agent atomics
// (global sc1, no L2 writeback/invalidate ops anywhere in the loop):
//   producer: data st_llc -> __syncthreads (vmcnt drained) -> flag st_llc
//   consumer: poll flags relaxed -> compiler barrier -> data ld_llc
// Cross-block vectors staged into LDS once (kills the 16x read replay).
__global__ void __launch_bounds__(NTHR, 1)
enas_controller(const float* __restrict__ g_emb,   // [1,1024]
                const float* __restrict__ w_emb,   // [8,1024]
                const float* __restrict__ w_soft,  // [2,1024]
                const float* __restrict__ w_ih,    // [2,4096,1024]
                const float* __restrict__ w_hh,    // [2,4096,1024]
                const float* __restrict__ b_ih,    // [2,4096]
                const float* __restrict__ b_hh,    // [2,4096]
                float* __restrict__ out,           // [98]
                float* __restrict__ ws) {          // >= WS_TOTAL floats, zeroed
  const int tid = threadIdx.x;
  const int b = blockIdx.x;
  const int row_idx = tid >> 5;
  const int sub = tid & 31;
  const int q = row_idx >> 2;
  const int j = row_idx & 3;
  const int row = q * HID + (b * 4 + j);  // gate row within one layer's 4096
  const int col0 = sub * 4;               // + i*128 interleave

  float* flags = ws + WS_FLAGS;           // epochs stored as float-typed words

  __shared__ __align__(16) float hxS[3 * HID];  // h1 | h0c0 | h0c1 (bufR image)
  __shared__ float xdotPre[16][3];  // [gate row][x in {emb0, emb1, g_emb}]
  __shared__ float bsumS[2][16];
  __shared__ float wsoftS[2][4];
  __shared__ float gatesS[16];      // layer-1 gate sums
  __shared__ float hdotS[16];       // W_hh0 @ h0  per gate row
  __shared__ float cS1[4];
  __shared__ float c0cand[2][4];
  __shared__ float hS[4];
  __shared__ float wredS[2][8];
  __shared__ int sampS;

  // ---- one-time: weights into registers (then PINNED) ----
  float4 Wih1[8], Whh1[8], Whh0[8];
  {
    const float* p_ih1 = w_ih + (size_t)(4096 + row) * HID;
    const float* p_hh0 = w_hh + (size_t)row * HID;
    const float* p_hh1 = w_hh + (size_t)(4096 + row) * HID;
#pragma unroll
    for (int i = 0; i < 8; ++i) {
      Wih1[i] = *(const float4*)(p_ih1 + col0 + i * 128);
      Whh0[i] = *(const float4*)(p_hh0 + col0 + i * 128);
      Whh1[i] = *(const float4*)(p_hh1 + col0 + i * 128);
    }
#pragma unroll
    for (int i = 0; i < 8; ++i) { PIN4(Wih1[i]); PIN4(Whh0[i]); PIN4(Whh1[i]); }
  }
  // ---- one-time: fold W_ih0 against the 3 possible inputs ----
  {
    const float* p_ih0 = w_ih + (size_t)row * HID;
    const float* xs[3] = {w_emb, w_emb + HID, g_emb};
#pragma unroll
    for (int vi = 0; vi < 3; ++vi) {
      float a = 0.0f;
#pragma unroll
      for (int i = 0; i < 8; ++i) {
        float4 wv = *(const float4*)(p_ih0 + col0 + i * 128);
        float4 xv = *(const float4*)(xs[vi] + col0 + i * 128);
        a = fmaf(wv.x, xv.x, a); a = fmaf(wv.y, xv.y, a);
        a = fmaf(wv.z, xv.z, a); a = fmaf(wv.w, xv.w, a);
      }
#pragma unroll
      for (int m = 16; m >= 1; m >>= 1) a += __shfl_xor(a, m, 64);
      if (sub == 0) xdotPre[row_idx][vi] = a;
    }
    if (tid < 32) {
      int l = tid >> 4, r = tid & 15;
      int rw = (r >> 2) * HID + b * 4 + (r & 3);
      bsumS[l][r] = b_ih[l * 4096 + rw] + b_hh[l * 4096 + rw];
    }
    if (tid < 8) wsoftS[tid >> 2][tid & 3] = w_soft[(tid >> 2) * HID + b * 4 + (tid & 3)];
    if (tid < 4) cS1[tid] = 0.0f;
  }
  __syncthreads();

  // ---- pre-loop: h0[0] = LSTM0(g_emb, h=0, c=0); publish into BUF(0) ----
  {
    float* bufW = ws;  // BUF(0)
    if (tid < 4) {
      float gi = xdotPre[tid][2] + bsumS[0][tid];
      float gg = xdotPre[8 + tid][2] + bsumS[0][8 + tid];
      float go = xdotPre[12 + tid][2] + bsumS[0][12 + tid];
      float cn = sigmoidf_(gi) * tanhf(gg);        // c=0 -> f-term vanishes
      float hn = sigmoidf_(go) * tanhf(cn);
      c0cand[0][tid] = cn;
      c0cand[1][tid] = cn;
      st_llc(&bufW[H0COFF + b * 4 + tid], hn);
      st_llc(&bufW[H0COFF + HID + b * 4 + tid], hn);
    }
    __syncthreads();  // drains vmcnt: candidate stores acked at LLC
    if (tid == 0) {
      asm volatile("s_waitcnt vmcnt(0)" ::: "memory");
      st_llc(&flags[b * 32], __uint_as_float(1u));
    }
  }

  float accE = 0.0f, accLP = 0.0f;

  for (int k = 0; k <= NSTEPS; ++k) {
    // ---- flat one-hop barrier: wait for all flags >= k+1 (relaxed polls) ----
    {
      const unsigned e = (unsigned)(k + 1);
      int ok;
      do {
        unsigned f = e;
        if (tid < NBLK)
          f = __float_as_uint(ld_llc(&flags[tid * 32]));
        ok = (f >= e);
      } while (!__syncthreads_and(ok));
      asm volatile("" ::: "memory");  // no reordering of data loads above poll
    }

    const float* bufR = ws + (size_t)(k & 1) * BUFSZ;
    float* bufW = ws + (size_t)((k + 1) & 1) * BUFSZ;

    // ---- stage bufR h-vectors (3072 floats) into LDS via sc1 loads ----
    {
      float stg[6];
#pragma unroll
      for (int w = 0; w < 6; ++w) stg[w] = ld_llc(&bufR[w * NTHR + tid]);
#pragma unroll
      for (int w = 0; w < 6; ++w) hxS[w * NTHR + tid] = stg[w];
    }
    // partial-logit loads for the sample reduction (overlap with staging)
    float v0 = 0.0f, v1 = 0.0f;
    if (k > 0 && tid < NBLK) {
      v0 = ld_llc(&bufR[POFF + tid]);
      v1 = ld_llc(&bufR[POFF + NBLK + tid]);
    }
    __syncthreads();  // hxS visible block-wide

    // ---- 5 sample-independent dot passes from LDS (weights pinned) ----
    const float* h1v = hxS;
    const float* h0c0 = hxS + HID;
    const float* h0c1 = hxS + 2 * HID;
    float aW1c0 = 0.0f, aW1c1 = 0.0f, aH0c0 = 0.0f, aH0c1 = 0.0f, aHH1 = 0.0f;
#pragma unroll
    for (int i = 0; i < 8; ++i) {
      float4 x0 = *(const float4*)(h0c0 + col0 + i * 128);
      float4 x1 = *(const float4*)(h0c1 + col0 + i * 128);
      float4 hh = *(const float4*)(h1v + col0 + i * 128);
      aW1c0 = fmaf(Wih1[i].x, x0.x, aW1c0); aW1c0 = fmaf(Wih1[i].y, x0.y, aW1c0);
      aW1c0 = fmaf(Wih1[i].z, x0.z, aW1c0); aW1c0 = fmaf(Wih1[i].w, x0.w, aW1c0);
      aW1c1 = fmaf(Wih1[i].x, x1.x, aW1c1); aW1c1 = fmaf(Wih1[i].y, x1.y, aW1c1);
      aW1c1 = fmaf(Wih1[i].z, x1.z, aW1c1); aW1c1 = fmaf(Wih1[i].w, x1.w, aW1c1);
      aH0c0 = fmaf(Whh0[i].x, x0.x, aH0c0); aH0c0 = fmaf(Whh0[i].y, x0.y, aH0c0);
      aH0c0 = fmaf(Whh0[i].z, x0.z, aH0c0); aH0c0 = fmaf(Whh0[i].w, x0.w, aH0c0);
      aH0c1 = fmaf(Whh0[i].x, x1.x, aH0c1); aH0c1 = fmaf(Whh0[i].y, x1.y, aH0c1);
      aH0c1 = fmaf(Whh0[i].z, x1.z, aH0c1); aH0c1 = fmaf(Whh0[i].w, x1.w, aH0c1);
      aHH1 = fmaf(Whh1[i].x, hh.x, aHH1); aHH1 = fmaf(Whh1[i].y, hh.y, aHH1);
      aHH1 = fmaf(Whh1[i].z, hh.z, aHH1); aHH1 = fmaf(Whh1[i].w, hh.w, aHH1);
    }

    // ---- sample[k-1]: redundant, bit-identical in every block ----
    int smp = 0;
    if (k > 0) {
#pragma unroll
      for (int m = 32; m >= 1; m >>= 1) {
        v0 += __shfl_xor(v0, m, 64);
        v1 += __shfl_xor(v1, m, 64);
      }
      if ((tid & 63) == 0) {
        wredS[0][tid >> 6] = v0;
        wredS[1][tid >> 6] = v1;
      }
      __syncthreads();
      if (tid == 0) {
        float t0 = ((wredS[0][0] + wredS[0][1]) + (wredS[0][2] + wredS[0][3])) +
                   ((wredS[0][4] + wredS[0][5]) + (wredS[0][6] + wredS[0][7]));
        float t1 = ((wredS[1][0] + wredS[1][1]) + (wredS[1][2] + wredS[1][3])) +
                   ((wredS[1][4] + wredS[1][5]) + (wredS[1][6] + wredS[1][7]));
        float l0 = 2.5f * tanhf(t0 / 5.0f);
        float l1 = 2.5f * tanhf(t1 / 5.0f);
        float m = fmaxf(l0, l1);
        float s0 = l0 - m, s1 = l1 - m;
        float lse = logf(expf(s0) + expf(s1));
        float lp0 = s0 - lse, lp1 = s1 - lse;
        uint32_t sk0, sk1, bt0, bt1, a, c;
        tf2x32(0u, 42u, 0u, (uint32_t)(k - 1), sk0, sk1);
        tf2x32(sk0, sk1, 0u, 0u, a, c); bt0 = a ^ c;
        tf2x32(sk0, sk1, 0u, 1u, a, c); bt1 = a ^ c;
        float gum0 = -logf(-logf(jax_uniform(bt0)));
        float gum1 = -logf(-logf(jax_uniform(bt1)));
        int sm = (gum1 + l1 > gum0 + l0) ? 1 : 0;
        accE += -(expf(lp0) * lp0 + expf(lp1) * lp1);
        accLP += sm ? lp1 : lp0;
        sampS = sm;
        if (b == 0) out[k - 1] = (float)sm;
      }
      __syncthreads();
      smp = sampS;
    }
    if (k == NSTEPS) break;

    // ---- select candidate (uniform cndmask) and reduce ----
    float a1 = (smp ? aW1c1 : aW1c0) + aHH1;
    float a0 = smp ? aH0c1 : aH0c0;
#pragma unroll
    for (int m = 16; m >= 1; m >>= 1) {
      a1 += __shfl_xor(a1, m, 64);
      a0 += __shfl_xor(a0, m, 64);
    }
    if (sub == 0) {
      gatesS[row_idx] = a1 + bsumS[1][row_idx];
      hdotS[row_idx] = a0;
    }
    __syncthreads();

    if (tid < 4) {
      // layer-1 cell -> h1[k] own units
      {
        float gi = gatesS[tid], gf = gatesS[4 + tid];
        float gg = gatesS[8 + tid], go = gatesS[12 + tid];
        float c = cS1[tid];
        float cn = sigmoidf_(gf) * c + sigmoidf_(gi) * tanhf(gg);
        float hn = sigmoidf_(go) * tanhf(cn);
        cS1[tid] = cn;
        hS[tid] = hn;
        st_llc(&bufW[H1OFF + b * 4 + tid], hn);
      }
      // layer-0 dual candidates for h0[k+1]
      float c0sel = c0cand[smp][tid];
#pragma unroll
      for (int jj = 0; jj < 2; ++jj) {
        float gi = xdotPre[tid][jj] + hdotS[tid] + bsumS[0][tid];
        float gf = xdotPre[4 + tid][jj] + hdotS[4 + tid] + bsumS[0][4 + tid];
        float gg = xdotPre[8 + tid][jj] + hdotS[8 + tid] + bsumS[0][8 + tid];
        float go = xdotPre[12 + tid][jj] + hdotS[12 + tid] + bsumS[0][12 + tid];
        float cn = sigmoidf_(gf) * c0sel + sigmoidf_(gi) * tanhf(gg);
        float hn = sigmoidf_(go) * tanhf(cn);
        c0cand[jj][tid] = cn;
        st_llc(&bufW[H0COFF + (size_t)jj * HID + b * 4 + tid], hn);
      }
      // partial logits (lane 0 reads hS written by lanes 0-3, same wave)
      if (tid == 0) {
        float p0 = wsoftS[0][0] * hS[0] + wsoftS[0][1] * hS[1] +
                   wsoftS[0][2] * hS[2] + wsoftS[0][3] * hS[3];
        float p1 = wsoftS[1][0] * hS[0] + wsoftS[1][1] * hS[1] +
                   wsoftS[1][2] * hS[2] + wsoftS[1][3] * hS[3];
        st_llc(&bufW[POFF + b], p0);
        st_llc(&bufW[POFF + NBLK + b], p1);
      }
    }
    __syncthreads();  // drains vmcnt: all exchange stores acked at LLC
    if (tid == 0) {
      asm volatile("s_waitcnt vmcnt(0)" ::: "memory");
      st_llc(&flags[b * 32], __uint_as_float((unsigned)(k + 2)));
    }
  }

  if (b == 0 && tid == 0) {
    out[96] = accE;
    out[97] = accLP;
  }
}

extern "C" void kernel_launch(void* const* d_in, const int* in_sizes, int n_in,
                              void* d_out, int out_size, void* d_ws, size_t ws_size,
                              hipStream_t stream) {
  const float* g_emb = (const float*)d_in[0];
  const float* w_emb = (const float*)d_in[1];
  const float* w_soft = (const float*)d_in[2];
  const float* w_ih = (const float*)d_in[3];
  const float* w_hh = (const float*)d_in[4];
  const float* b_ih = (const float*)d_in[5];
  const float* b_hh = (const float*)d_in[6];
  float* out = (float*)d_out;
  float* ws = (float*)d_ws;

  // flags + exchange buffers must start zeroed (harness poisons ws with 0xAA)
  hipMemsetAsync(ws, 0, WS_TOTAL * sizeof(float), stream);

  enas_controller<<<dim3(NBLK), dim3(NTHR), 0, stream>>>(
      g_emb, w_emb, w_soft, w_ih, w_hh, b_ih, b_hh, out, ws);
}

// Round 8
// 582.048 us; speedup vs baseline: 11.5695x; 1.2312x over previous
//
#include <hip/hip_runtime.h>
#include <cstdint>
#include <cstddef>

#define NSTEPS 96
#define HID 1024
#define NBLK 256
#define NTHR 512

// ws float offsets. Double-buffered exchange: BUF(p) = p*3584
//   +0    : [1024]    h1[k]
//   +1024 : [2][1024] h0[k+1] candidates (by sample value)
//   +3072 : [2][256]  per-block partial logits of h1[k]
#define BUFSZ 3584
#define H1OFF 0
#define H0COFF 1024
#define POFF 3072
#define WS_FLAGS 7168         // 256 flags, stride 32 floats (128B)
#define WS_TOTAL 15360

// Opaque register pin: value becomes asm-defined -> cannot be rematerialized
// from memory, must stay live in VGPRs across the step loop.
#define PIN4(v) asm volatile("" : "+v"(v.x), "+v"(v.y), "+v"(v.z), "+v"(v.w))

// Relaxed agent-scope ops: plain global_load/store (sc1 -> LLC, the coherence
// point) with NO buffer_wbl2/buffer_inv cache maintenance.
__device__ __forceinline__ float ld_llc(const float* p) {
  return __hip_atomic_load(p, __ATOMIC_RELAXED, __HIP_MEMORY_SCOPE_AGENT);
}
__device__ __forceinline__ void st_llc(float* p, float v) {
  __hip_atomic_store(p, v, __ATOMIC_RELAXED, __HIP_MEMORY_SCOPE_AGENT);
}

// ---------------- Threefry-2x32-20 (exact JAX algorithm) ----------------
__device__ __forceinline__ void tf2x32(uint32_t k0, uint32_t k1,
                                       uint32_t x0, uint32_t x1,
                                       uint32_t& o0, uint32_t& o1) {
  uint32_t ks[3] = {k0, k1, k0 ^ k1 ^ 0x1BD11BDAu};
  x0 += ks[0];
  x1 += ks[1];
  const uint32_t R[2][4] = {{13u, 15u, 26u, 6u}, {17u, 29u, 16u, 24u}};
#pragma unroll
  for (int i = 0; i < 5; ++i) {
#pragma unroll
    for (int r = 0; r < 4; ++r) {
      uint32_t rot = R[i & 1][r];
      x0 += x1;
      x1 = (x1 << rot) | (x1 >> (32u - rot));
      x1 ^= x0;
    }
    x0 += ks[(i + 1) % 3];
    x1 += ks[(i + 2) % 3] + (uint32_t)(i + 1);
  }
  o0 = x0;
  o1 = x1;
}

__device__ __forceinline__ float jax_uniform(uint32_t bits) {
  const float TINY = 1.17549435e-38f;
  float f = __uint_as_float((bits >> 9) | 0x3f800000u) - 1.0f;
  f = f * (1.0f - TINY) + TINY;
  return fmaxf(TINY, f);
}

__device__ __forceinline__ float sigmoidf_(float x) {
  return 1.0f / (1.0f + expf(-x));
}

// 256 blocks x 512 threads; block b owns hidden units [4b,4b+4) of both
// layers. W_ih1/W_hh1/W_hh0 slices pinned in VGPRs; W_ih0 folded away; all
// 96 gumbel pairs precomputed at setup (threefry off the critical path).
// ONE flat grid barrier/step, relaxed sc1 atomics only. Wave 0 polls flags
// (no per-iteration block barrier), reduces partial logits in-wave, samples,
// and runs all 3 LSTM cells on 12 parallel lanes. 3 __syncthreads/step.
__global__ void __launch_bounds__(NTHR, 1)
enas_controller(const float* __restrict__ g_emb,   // [1,1024]
                const float* __restrict__ w_emb,   // [8,1024]
                const float* __restrict__ w_soft,  // [2,1024]
                const float* __restrict__ w_ih,    // [2,4096,1024]
                const float* __restrict__ w_hh,    // [2,4096,1024]
                const float* __restrict__ b_ih,    // [2,4096]
                const float* __restrict__ b_hh,    // [2,4096]
                float* __restrict__ out,           // [98]
                float* __restrict__ ws) {          // >= WS_TOTAL floats, zeroed
  const int tid = threadIdx.x;
  const int b = blockIdx.x;
  const int row_idx = tid >> 5;
  const int sub = tid & 31;
  const int q = row_idx >> 2;
  const int j = row_idx & 3;
  const int row = q * HID + (b * 4 + j);  // gate row within one layer's 4096
  const int col0 = sub * 4;               // + i*128 interleave

  float* flags = ws + WS_FLAGS;           // epochs stored as float-typed words

  __shared__ __align__(16) float hxS[3 * HID];  // h1 | h0c0 | h0c1 (bufR image)
  __shared__ float gumS[2 * NSTEPS];            // precomputed gumbels
  __shared__ float xdotPre[16][3];  // [gate row][x in {emb0, emb1, g_emb}]
  __shared__ float bsumS[2][16];
  __shared__ float wsoftS[2][4];
  __shared__ float dotS[16][4];     // per gate row: {L1|c0, L1|c1, hh0|c0, hh0|c1}
  __shared__ float cS1[4];
  __shared__ float c0cand[2][4];
  __shared__ float hS[4];

  // ---- one-time: weights into registers (then PINNED) ----
  float4 Wih1[8], Whh1[8], Whh0[8];
  {
    const float* p_ih1 = w_ih + (size_t)(4096 + row) * HID;
    const float* p_hh0 = w_hh + (size_t)row * HID;
    const float* p_hh1 = w_hh + (size_t)(4096 + row) * HID;
#pragma unroll
    for (int i = 0; i < 8; ++i) {
      Wih1[i] = *(const float4*)(p_ih1 + col0 + i * 128);
      Whh0[i] = *(const float4*)(p_hh0 + col0 + i * 128);
      Whh1[i] = *(const float4*)(p_hh1 + col0 + i * 128);
    }
#pragma unroll
    for (int i = 0; i < 8; ++i) { PIN4(Wih1[i]); PIN4(Whh0[i]); PIN4(Whh1[i]); }
  }
  // ---- one-time: fold W_ih0; biases; wsoft; gumbels ----
  {
    const float* p_ih0 = w_ih + (size_t)row * HID;
    const float* xs[3] = {w_emb, w_emb + HID, g_emb};
#pragma unroll
    for (int vi = 0; vi < 3; ++vi) {
      float a = 0.0f;
#pragma unroll
      for (int i = 0; i < 8; ++i) {
        float4 wv = *(const float4*)(p_ih0 + col0 + i * 128);
        float4 xv = *(const float4*)(xs[vi] + col0 + i * 128);
        a = fmaf(wv.x, xv.x, a); a = fmaf(wv.y, xv.y, a);
        a = fmaf(wv.z, xv.z, a); a = fmaf(wv.w, xv.w, a);
      }
#pragma unroll
      for (int m = 16; m >= 1; m >>= 1) a += __shfl_xor(a, m, 64);
      if (sub == 0) xdotPre[row_idx][vi] = a;
    }
    if (tid < 96) {  // all 96 steps' gumbel pairs, in parallel, once
      uint32_t sk0, sk1, a, c, b0, b1;
      tf2x32(0u, 42u, 0u, (uint32_t)tid, sk0, sk1);
      tf2x32(sk0, sk1, 0u, 0u, a, c); b0 = a ^ c;
      tf2x32(sk0, sk1, 0u, 1u, a, c); b1 = a ^ c;
      gumS[2 * tid] = -logf(-logf(jax_uniform(b0)));
      gumS[2 * tid + 1] = -logf(-logf(jax_uniform(b1)));
    }
    if (tid < 32) {
      int l = tid >> 4, r = tid & 15;
      int rw = (r >> 2) * HID + b * 4 + (r & 3);
      bsumS[l][r] = b_ih[l * 4096 + rw] + b_hh[l * 4096 + rw];
    }
    if (tid < 8) wsoftS[tid >> 2][tid & 3] = w_soft[(tid >> 2) * HID + b * 4 + (tid & 3)];
    if (tid < 4) cS1[tid] = 0.0f;
  }
  __syncthreads();

  // ---- pre-loop: h0[0] = LSTM0(g_emb, h=0, c=0); publish into BUF(0) ----
  {
    float* bufW = ws;  // BUF(0)
    if (tid < 4) {
      float gi = xdotPre[tid][2] + bsumS[0][tid];
      float gg = xdotPre[8 + tid][2] + bsumS[0][8 + tid];
      float go = xdotPre[12 + tid][2] + bsumS[0][12 + tid];
      float cn = sigmoidf_(gi) * tanhf(gg);        // c=0 -> f-term vanishes
      float hn = sigmoidf_(go) * tanhf(cn);
      c0cand[0][tid] = cn;
      c0cand[1][tid] = cn;
      st_llc(&bufW[H0COFF + b * 4 + tid], hn);
      st_llc(&bufW[H0COFF + HID + b * 4 + tid], hn);
    }
    __syncthreads();  // compiler drains vmcnt before s_barrier
    if (tid == 0) {
      asm volatile("s_waitcnt vmcnt(0)" ::: "memory");
      st_llc(&flags[b * 32], __uint_as_float(1u));
    }
  }

  float accE = 0.0f, accLP = 0.0f;

  for (int k = 0; k < NSTEPS; ++k) {
    // ---- #1: wave-0 poll (relaxed, no block barrier per iter) ----
    {
      const unsigned e = (unsigned)(k + 1);
      if (tid < 64) {
        int ok;
        do {
          ok = 1;
#pragma unroll
          for (int t = 0; t < 4; ++t)
            ok &= (__float_as_uint(ld_llc(&flags[(tid + t * 64) * 32])) >= e);
        } while (!__all(ok));
      }
      __syncthreads();
      asm volatile("" ::: "memory");
    }

    const float* bufR = ws + (size_t)(k & 1) * BUFSZ;
    float* bufW = ws + (size_t)((k + 1) & 1) * BUFSZ;

    // ---- stage h-vectors into LDS; wave0 also loads logit partials ----
    float stg[6];
#pragma unroll
    for (int w = 0; w < 6; ++w) stg[w] = ld_llc(&bufR[w * NTHR + tid]);
    float pv0[4], pv1[4];
    if (tid < 64) {
#pragma unroll
      for (int t = 0; t < 4; ++t) {
        pv0[t] = ld_llc(&bufR[POFF + tid + t * 64]);
        pv1[t] = ld_llc(&bufR[POFF + NBLK + tid + t * 64]);
      }
    }
#pragma unroll
    for (int w = 0; w < 6; ++w) hxS[w * NTHR + tid] = stg[w];
    __syncthreads();  // #2: hxS visible

    // ---- 5 sample-independent dot passes from LDS (weights pinned) ----
    const float* h1v = hxS;
    const float* h0c0 = hxS + HID;
    const float* h0c1 = hxS + 2 * HID;
    float aW1c0 = 0.0f, aW1c1 = 0.0f, aH0c0 = 0.0f, aH0c1 = 0.0f, aHH1 = 0.0f;
#pragma unroll
    for (int i = 0; i < 8; ++i) {
      float4 x0 = *(const float4*)(h0c0 + col0 + i * 128);
      float4 x1 = *(const float4*)(h0c1 + col0 + i * 128);
      float4 hh = *(const float4*)(h1v + col0 + i * 128);
      aW1c0 = fmaf(Wih1[i].x, x0.x, aW1c0); aW1c0 = fmaf(Wih1[i].y, x0.y, aW1c0);
      aW1c0 = fmaf(Wih1[i].z, x0.z, aW1c0); aW1c0 = fmaf(Wih1[i].w, x0.w, aW1c0);
      aW1c1 = fmaf(Wih1[i].x, x1.x, aW1c1); aW1c1 = fmaf(Wih1[i].y, x1.y, aW1c1);
      aW1c1 = fmaf(Wih1[i].z, x1.z, aW1c1); aW1c1 = fmaf(Wih1[i].w, x1.w, aW1c1);
      aH0c0 = fmaf(Whh0[i].x, x0.x, aH0c0); aH0c0 = fmaf(Whh0[i].y, x0.y, aH0c0);
      aH0c0 = fmaf(Whh0[i].z, x0.z, aH0c0); aH0c0 = fmaf(Whh0[i].w, x0.w, aH0c0);
      aH0c1 = fmaf(Whh0[i].x, x1.x, aH0c1); aH0c1 = fmaf(Whh0[i].y, x1.y, aH0c1);
      aH0c1 = fmaf(Whh0[i].z, x1.z, aH0c1); aH0c1 = fmaf(Whh0[i].w, x1.w, aH0c1);
      aHH1 = fmaf(Whh1[i].x, hh.x, aHH1); aHH1 = fmaf(Whh1[i].y, hh.y, aHH1);
      aHH1 = fmaf(Whh1[i].z, hh.z, aHH1); aHH1 = fmaf(Whh1[i].w, hh.w, aHH1);
    }
    // butterfly ALL 5 now (before sample known) -> trivial select later
#pragma unroll
    for (int m = 16; m >= 1; m >>= 1) {
      aW1c0 += __shfl_xor(aW1c0, m, 64);
      aW1c1 += __shfl_xor(aW1c1, m, 64);
      aH0c0 += __shfl_xor(aH0c0, m, 64);
      aH0c1 += __shfl_xor(aH0c1, m, 64);
      aHH1 += __shfl_xor(aHH1, m, 64);
    }
    if (sub == 0) {
      float gb = bsumS[1][row_idx];
      dotS[row_idx][0] = aW1c0 + aHH1 + gb;
      dotS[row_idx][1] = aW1c1 + aHH1 + gb;
      dotS[row_idx][2] = aH0c0;
      dotS[row_idx][3] = aH0c1;
    }

    // ---- wave-0: sample[k-1] (in-wave reduce, gumbels from LDS) ----
    int sm = 0;
    float l0 = 0.0f, l1 = 0.0f;
    if (tid < 64 && k > 0) {
      float v0 = (pv0[0] + pv0[1]) + (pv0[2] + pv0[3]);
      float v1 = (pv1[0] + pv1[1]) + (pv1[2] + pv1[3]);
#pragma unroll
      for (int m = 32; m >= 1; m >>= 1) {
        v0 += __shfl_xor(v0, m, 64);
        v1 += __shfl_xor(v1, m, 64);
      }
      if (tid == 0) {
        l0 = 2.5f * tanhf(v0 / 5.0f);
        l1 = 2.5f * tanhf(v1 / 5.0f);
        sm = (gumS[2 * (k - 1) + 1] + l1 > gumS[2 * (k - 1)] + l0) ? 1 : 0;
        if (b == 0) out[k - 1] = (float)sm;
      }
      sm = __shfl(sm, 0, 64);
    }
    __syncthreads();  // #3: dotS complete (all waves)

    // ---- wave-0 lanes 0-11: all three LSTM cells in parallel ----
    if (tid < 12) {
      const int cell = tid >> 2, t = tid & 3;
      if (cell == 0) {  // layer-1 cell, unit t
        float gi = dotS[t][sm], gf = dotS[4 + t][sm];
        float gg = dotS[8 + t][sm], go = dotS[12 + t][sm];
        float c = cS1[t];
        float cn = sigmoidf_(gf) * c + sigmoidf_(gi) * tanhf(gg);
        float hn = sigmoidf_(go) * tanhf(cn);
        cS1[t] = cn;
        hS[t] = hn;
        st_llc(&bufW[H1OFF + b * 4 + t], hn);
      } else {  // layer-0 candidate jj = cell-1, unit t
        const int jj = cell - 1;
        float gi = xdotPre[t][jj] + dotS[t][2 + sm] + bsumS[0][t];
        float gf = xdotPre[4 + t][jj] + dotS[4 + t][2 + sm] + bsumS[0][4 + t];
        float gg = xdotPre[8 + t][jj] + dotS[8 + t][2 + sm] + bsumS[0][8 + t];
        float go = xdotPre[12 + t][jj] + dotS[12 + t][2 + sm] + bsumS[0][12 + t];
        float c0sel = c0cand[sm][t];          // read (lockstep) ...
        float cn = sigmoidf_(gf) * c0sel + sigmoidf_(gi) * tanhf(gg);
        float hn = sigmoidf_(go) * tanhf(cn);
        c0cand[jj][t] = cn;                   // ... then write
        st_llc(&bufW[H0COFF + (size_t)jj * HID + b * 4 + t], hn);
      }
    }
    if (tid == 0) {
      float p0 = wsoftS[0][0] * hS[0] + wsoftS[0][1] * hS[1] +
                 wsoftS[0][2] * hS[2] + wsoftS[0][3] * hS[3];
      float p1 = wsoftS[1][0] * hS[0] + wsoftS[1][1] * hS[1] +
                 wsoftS[1][2] * hS[2] + wsoftS[1][3] * hS[3];
      st_llc(&bufW[POFF + b], p0);
      st_llc(&bufW[POFF + NBLK + b], p1);
      asm volatile("s_waitcnt vmcnt(0)" ::: "memory");  // wave-wide drain
      st_llc(&flags[b * 32], __uint_as_float((unsigned)(k + 2)));
      // off-critical-path: entropy / log-prob accumulation (block 0 only)
      if (b == 0 && k > 0) {
        float mm = fmaxf(l0, l1);
        float s0 = l0 - mm, s1 = l1 - mm;
        float lse = logf(expf(s0) + expf(s1));
        float lp0 = s0 - lse, lp1 = s1 - lse;
        accE += -(expf(lp0) * lp0 + expf(lp1) * lp1);
        accLP += sm ? lp1 : lp0;
      }
    }
  }

  // ---- final: sample 95 + output writes (block 0 only) ----
  if (b == 0 && tid < 64) {
    const unsigned e = (unsigned)(NSTEPS + 1);
    int ok;
    do {
      ok = 1;
#pragma unroll
      for (int t = 0; t < 4; ++t)
        ok &= (__float_as_uint(ld_llc(&flags[(tid + t * 64) * 32])) >= e);
    } while (!__all(ok));
    asm volatile("" ::: "memory");
    const float* bufR = ws + (size_t)(NSTEPS & 1) * BUFSZ;
    float pv0[4], pv1[4];
#pragma unroll
    for (int t = 0; t < 4; ++t) {
      pv0[t] = ld_llc(&bufR[POFF + tid + t * 64]);
      pv1[t] = ld_llc(&bufR[POFF + NBLK + tid + t * 64]);
    }
    float v0 = (pv0[0] + pv0[1]) + (pv0[2] + pv0[3]);
    float v1 = (pv1[0] + pv1[1]) + (pv1[2] + pv1[3]);
#pragma unroll
    for (int m = 32; m >= 1; m >>= 1) {
      v0 += __shfl_xor(v0, m, 64);
      v1 += __shfl_xor(v1, m, 64);
    }
    if (tid == 0) {
      float l0 = 2.5f * tanhf(v0 / 5.0f);
      float l1 = 2.5f * tanhf(v1 / 5.0f);
      int sm = (gumS[2 * 95 + 1] + l1 > gumS[2 * 95] + l0) ? 1 : 0;
      float mm = fmaxf(l0, l1);
      float s0 = l0 - mm, s1 = l1 - mm;
      float lse = logf(expf(s0) + expf(s1));
      float lp0 = s0 - lse, lp1 = s1 - lse;
      accE += -(expf(lp0) * lp0 + expf(lp1) * lp1);
      accLP += sm ? lp1 : lp0;
      out[95] = (float)sm;
      out[96] = accE;
      out[97] = accLP;
    }
  }
}

extern "C" void kernel_launch(void* const* d_in, const int* in_sizes, int n_in,
                              void* d_out, int out_size, void* d_ws, size_t ws_size,
                              hipStream_t stream) {
  const float* g_emb = (const float*)d_in[0];
  const float* w_emb = (const float*)d_in[1];
  const float* w_soft = (const float*)d_in[2];
  const float* w_ih = (const float*)d_in[3];
  const float* w_hh = (const float*)d_in[4];
  const float* b_ih = (const float*)d_in[5];
  const float* b_hh = (const float*)d_in[6];
  float* out = (float*)d_out;
  float* ws = (float*)d_ws;

  // flags + exchange buffers must start zeroed (harness poisons ws with 0xAA)
  hipMemsetAsync(ws, 0, WS_TOTAL * sizeof(float), stream);

  enas_controller<<<dim3(NBLK), dim3(NTHR), 0, stream>>>(
      g_emb, w_emb, w_soft, w_ih, w_hh, b_ih, b_hh, out, ws);
}